// Round 6
// baseline (340.114 us; speedup 1.0000x reference)
//
#include <hip/hip_runtime.h>
#include <math.h>

#define N_NODES 50000
#define N_EDGES 600000
#define F 128
#define NT 4
#define NKTG 20                // K tiles of 32 (640 total K)
#define NCT 8                  // out-col tiles of 16 (128/16)
#define N_SEG (NT * N_NODES)   // 200000
#define SCAN_BLK 196           // ceil(N_SEG / 1024)
#define WELEM (NKTG * NCT * 64 * 8)  // 81920 fp16 elements per layer
#define PER_LAYER (NKTG * NCT * 64)  // 10240 weight fragments
#define BW_BLOCKS 81           // build_w portion of prep grid (81*256 = 20736)
#define CAST_BLOCKS 12500      // cast portion (3.2M u32 / 256)

typedef __attribute__((ext_vector_type(8))) _Float16 f16x8;
typedef __attribute__((ext_vector_type(4))) float f32x4;

__device__ __forceinline__ unsigned short f2h(float f) {
    _Float16 h = (_Float16)f;
    return __builtin_bit_cast(unsigned short, h);
}
__device__ __forceinline__ float h2f(unsigned short u) {
    return (float)__builtin_bit_cast(_Float16, u);
}
__device__ __forceinline__ unsigned pack2h(float a, float b) {
    return (unsigned)f2h(a) | ((unsigned)f2h(b) << 16);
}

// ---- prep: build combined weights (fp16 hi/lo, frag order) + bias + cast x ----
__global__ __launch_bounds__(256) void prep(
    const float* __restrict__ x,
    const float* __restrict__ Ws1, const float* __restrict__ Wn1, const float* __restrict__ b1,
    const float* __restrict__ Ws2, const float* __restrict__ Wn2, const float* __restrict__ b2,
    unsigned short* __restrict__ x16,
    unsigned short* __restrict__ Wh, unsigned short* __restrict__ Wl,
    float* __restrict__ bavg)
{
    if (blockIdx.x >= BW_BLOCKS) {
        int i = (blockIdx.x - BW_BLOCKS) * 256 + threadIdx.x;
        if (i < N_NODES * 64) {
            float2 v = ((const float2*)x)[i];
            ((unsigned*)x16)[i] = pack2h(v.x, v.y);
        }
        return;
    }
    int idx = blockIdx.x * 256 + threadIdx.x;
    if (idx < 2 * PER_LAYER) {
        int l = idx >= PER_LAYER;
        int rem = idx - l * PER_LAYER;
        int lane = rem & 63;
        int ct = (rem >> 6) & 7;
        int ktg = (rem >> 6) >> 3;
        const float* Wsl = l ? Ws2 : Ws1;
        const float* Wnl = l ? Wn2 : Wn1;
        unsigned short* oh = Wh + (size_t)l * WELEM + (size_t)rem * 8;
        unsigned short* ol = Wl + (size_t)l * WELEM + (size_t)rem * 8;
        int c = ct * 16 + (lane & 15);
        int kb = ktg * 32 + (lane >> 4) * 8;
#pragma unroll
        for (int j = 0; j < 8; ++j) {
            int k = kb + j;
            float v;
            if (k < F) {
                v = 0.25f * (Wsl[(0 * F + k) * F + c] + Wsl[(1 * F + k) * F + c] +
                             Wsl[(2 * F + k) * F + c] + Wsl[(3 * F + k) * F + c]);
            } else {
                int t = (k - F) >> 7;
                int kk = (k - F) & (F - 1);
                v = 0.25f * Wnl[((size_t)t * F + kk) * F + c];
            }
            _Float16 hh = (_Float16)v;
            oh[j] = __builtin_bit_cast(unsigned short, hh);
            ol[j] = f2h(v - (float)hh);
        }
    } else {
        int k = idx - 2 * PER_LAYER;
        if (k < 2 * F) {
            int l = k >> 7;
            int j = k & (F - 1);
            const float* bl = l ? b2 : b1;
            bavg[k] = 0.25f * (bl[j] + bl[F + j] + bl[2 * F + j] + bl[3 * F + j]);
        }
    }
}

// ---------------- CSR build: seg = dst*4 + t ----------------
__global__ __launch_bounds__(256) void hist_kernel(
    const int* __restrict__ dstA, const int* __restrict__ typA, int* __restrict__ counts)
{
    int e = blockIdx.x * 256 + threadIdx.x;
    if (e < N_EDGES) atomicAdd(&counts[dstA[e] * NT + typA[e]], 1);
}

__global__ __launch_bounds__(256) void scan1(int* __restrict__ counts, int* __restrict__ bsum)
{
    __shared__ int sh[256];
    int t = threadIdx.x;
    int base = blockIdx.x * 1024 + t * 4;
    int v[4];
    int tot = 0;
#pragma unroll
    for (int j = 0; j < 4; ++j) {
        int i = base + j;
        v[j] = (i < N_SEG) ? counts[i] : 0;
        tot += v[j];
    }
    sh[t] = tot;
    __syncthreads();
    for (int ofs = 1; ofs < 256; ofs <<= 1) {
        int add = (t >= ofs) ? sh[t - ofs] : 0;
        __syncthreads();
        sh[t] += add;
        __syncthreads();
    }
    int excl = (t > 0) ? sh[t - 1] : 0;
    if (t == 255) bsum[blockIdx.x] = sh[255];
#pragma unroll
    for (int j = 0; j < 4; ++j) {
        int i = base + j;
        if (i < N_SEG) counts[i] = excl;
        excl += v[j];
    }
}

__global__ __launch_bounds__(256) void scan2(int* __restrict__ bsum)
{
    __shared__ int sh[256];
    int t = threadIdx.x;
    sh[t] = (t < SCAN_BLK) ? bsum[t] : 0;
    __syncthreads();
    for (int ofs = 1; ofs < 256; ofs <<= 1) {
        int add = (t >= ofs) ? sh[t - ofs] : 0;
        __syncthreads();
        sh[t] += add;
        __syncthreads();
    }
    int excl = (t > 0) ? sh[t - 1] : 0;
    if (t < SCAN_BLK) bsum[t] = excl;
}

// finalize offsets in place; pad [N_SEG, N_SEG+256] with N_EDGES so the fused
// kernel's per-wave boundary loads past the last real node read empty segments
__global__ __launch_bounds__(256) void scan3(
    int* __restrict__ counts, const int* __restrict__ bsum, int* __restrict__ cursor)
{
    int i = blockIdx.x * 256 + threadIdx.x;
    if (i < N_SEG) {
        int v = counts[i] + bsum[i >> 10];
        counts[i] = v;
        cursor[i] = v;
    } else if (i <= N_SEG + 256) {
        counts[i] = N_EDGES;
    }
}

// permute: bucket-sorted edges; payload = H-row dword offset (src*64)
__global__ __launch_bounds__(256) void permute_kernel(
    const int* __restrict__ srcA, const int* __restrict__ dstA, const int* __restrict__ typA,
    int* __restrict__ cursor, unsigned* __restrict__ perm)
{
    int e = blockIdx.x * 256 + threadIdx.x;
    if (e < N_EDGES) {
        int t = typA[e];
        int seg = dstA[e] * NT + t;
        int pos = atomicAdd(&cursor[seg], 1);
        perm[pos] = (unsigned)(srcA[e] * 64);
    }
}

// ================== fused layer (64-node tiles, 8 waves) ==================
// out[N,128] = [H | mean_t(H[src])][N,640] @ B[640,128] + bias (+norm/relu)
// Phase 1: stage H-self tile + chain-free double-buffered gather of per-
// (node,type) means into the LDS A-tile (scale applied at flush, from the
// boundary vector). One barrier. Phase 2: 20-K-tile MFMA GEMM + epilogue.

// flush current segment's mean into the LDS Agg tile
#define FLUSH_SEG() do {                                                      \
    float inv_ = 1.0f / fmaxf((float)(nextB - segStart), 1.0f);               \
    AGd[(w << 3) + (cur >> 2)][((cur & 3) << 6) + lane] =                     \
        pack2h(accx * inv_, accy * inv_);                                     \
    accx = 0.f; accy = 0.f;                                                   \
    segStart = nextB;                                                         \
    cur++;                                                                    \
    nextB = __builtin_amdgcn_readlane(vb, cur + 1 < 32 ? cur + 1 : 32);       \
} while (0)

// advance the 64-entry perm window so the batch starting at EN is fully inside
#define ADVW(EN) do {                                                         \
    if ((EN) - pbase >= 64) {                                                 \
        pbase += 64;                                                          \
        P0 = P1;                                                              \
        int i2_ = pbase + 64 + lane;                                          \
        i2_ = i2_ < N_EDGES - 1 ? i2_ : N_EDGES - 1;                          \
        P1 = P[i2_];                                                          \
    }                                                                         \
} while (0)

// issue 16-deep batch B_ into (UV, NB)
#define ISSUE(B_, UV, NB) do {                                                \
    int e_ = s0 + ((B_) << 4);                                                \
    int r_ = eend - e_;                                                       \
    NB = r_ > 16 ? 16 : (r_ > 0 ? r_ : 0);                                    \
    _Pragma("unroll")                                                         \
    for (int j_ = 0; j_ < 16; ++j_) {                                         \
        if (j_ < NB) {                                                        \
            int idx_ = e_ + j_ - pbase;                                       \
            unsigned ow_ = (unsigned)__builtin_amdgcn_readlane((int)P0, idx_); \
            UV[j_] = H32[(size_t)ow_ + lane];                                 \
        }                                                                     \
    }                                                                         \
} while (0)

// consume batch B_ (flush at segment boundaries)
#define CONSUME(B_, UV, NB) do {                                              \
    int e_ = s0 + ((B_) << 4);                                                \
    _Pragma("unroll")                                                         \
    for (int j_ = 0; j_ < 16; ++j_) {                                         \
        if (j_ < NB) {                                                        \
            int ge_ = e_ + j_;                                                \
            while (ge_ >= nextB) { FLUSH_SEG(); }                             \
            accx += h2f((unsigned short)(UV[j_] & 0xffffu));                  \
            accy += h2f((unsigned short)(UV[j_] >> 16));                      \
        }                                                                     \
    }                                                                         \
} while (0)

__global__ __launch_bounds__(512) void fused_layer(
    const unsigned short* __restrict__ Hin,   // [N,128] fp16 (self + gather source)
    const unsigned* __restrict__ perm,        // bucketed H-row dword offsets
    const int* __restrict__ off,              // [N_SEG+257], tail = N_EDGES
    const unsigned short* __restrict__ Wh,    // frag-ordered fp16 hi (this layer)
    const unsigned short* __restrict__ Wl,    // frag-ordered fp16 lo
    const float* __restrict__ bias,           // 128 fp32
    float* __restrict__ outF,                 // fp32 output (layer 2)
    unsigned short* __restrict__ outH,        // fp16 output (layer 1: norm+relu)
    int doNormRelu)
{
    __shared__ unsigned short HS[64][136];    // H-self tile (K chunks 0..3), padded
    __shared__ unsigned AGd[64][261];         // Agg tile [64 nodes][512 halves], dword view
    __shared__ float rs[64][8];               // row sumsq partials (L1 epilogue)

    const int tid = threadIdx.x;
    const int lane = tid & 63;
    const int w = tid >> 6;                   // 0..7
    const int quad = lane >> 4;
    const int l15 = lane & 15;
    const int nodeBase = blockIdx.x * 64;

    // ---- stage H-self tile (coalesced) ----
    {
        int r = tid >> 3;                     // 0..63
        int cb = (tid & 7) * 16;
        int n = nodeBase + r;
        int nc = n < N_NODES ? n : N_NODES - 1;
        const unsigned short* sp = Hin + (size_t)nc * F + cb;
        *(uint4*)&HS[r][cb]     = *(const uint4*)sp;
        *(uint4*)&HS[r][cb + 8] = *(const uint4*)(sp + 8);
    }

    // ---- gather phase: per-wave 8 nodes = 32 (node,type) segments ----
    const unsigned* H32 = (const unsigned*)Hin;
    const unsigned* P = perm;
    const int n0 = nodeBase + w * 8;

    int bl = lane < 32 ? lane : 32;
    int vb = off[n0 * 4 + bl];                // 33 segment boundaries

    int s0   = __builtin_amdgcn_readfirstlane(vb);
    int eend = __builtin_amdgcn_readlane(vb, 32);

    int pbase = s0;
    int i0 = pbase + lane;          i0 = i0 < N_EDGES - 1 ? i0 : N_EDGES - 1;
    int i1 = pbase + 64 + lane;     i1 = i1 < N_EDGES - 1 ? i1 : N_EDGES - 1;
    unsigned P0 = P[i0];
    unsigned P1 = P[i1];

    int cur = 0;
    int segStart = s0;
    int nextB = __builtin_amdgcn_readlane(vb, 1);
    float accx = 0.f, accy = 0.f;

    int nBatch = (eend - s0 + 15) >> 4;
    if (nBatch > 0) {
        unsigned uvA[16], uvB[16];
        int nbA, nbB;

        ISSUE(0, uvA, nbA);

        int b = 0;
        while (true) {
            if (b + 1 < nBatch) {
                ADVW(s0 + ((b + 1) << 4));
                ISSUE(b + 1, uvB, nbB);
            } else nbB = 0;
            CONSUME(b, uvA, nbA);
            if (++b >= nBatch) break;

            if (b + 1 < nBatch) {
                ADVW(s0 + ((b + 1) << 4));
                ISSUE(b + 1, uvA, nbA);
            } else nbA = 0;
            CONSUME(b, uvB, nbB);
            if (++b >= nBatch) break;
        }
    }
    while (cur < 32) { FLUSH_SEG(); }         // flush trailing empty segments

    __syncthreads();                          // Agg + H-self staged

    // ---- GEMM phase: [64,640] @ [640,128] from LDS; wave w -> col-tile w ----
    f32x4 acc[4];
#pragma unroll
    for (int rt = 0; rt < 4; ++rt)
        acc[rt] = (f32x4){0.f, 0.f, 0.f, 0.f};

    const f16x8* BH = (const f16x8*)Wh;
    const f16x8* BL = (const f16x8*)Wl;

#pragma unroll 4
    for (int ktg = 0; ktg < NKTG; ++ktg) {
        int fi = (ktg * NCT + w) * 64 + lane;
        f16x8 bh  = BH[fi];
        f16x8 blo = BL[fi];
        f16x8 ah[4];
        if (ktg < 4) {
#pragma unroll
            for (int rt = 0; rt < 4; ++rt)
                ah[rt] = *(const f16x8*)&HS[rt * 16 + l15][ktg * 32 + quad * 8];
        } else {
#pragma unroll
            for (int rt = 0; rt < 4; ++rt) {
                int row = rt * 16 + l15;
                int cd = ((ktg - 4) << 4) + (quad << 2);
                uint4 t4;
                t4.x = AGd[row][cd];
                t4.y = AGd[row][cd + 1];
                t4.z = AGd[row][cd + 2];
                t4.w = AGd[row][cd + 3];
                ah[rt] = __builtin_bit_cast(f16x8, t4);
            }
        }
#pragma unroll
        for (int rt = 0; rt < 4; ++rt) {
            acc[rt] = __builtin_amdgcn_mfma_f32_16x16x32_f16(ah[rt], bh,  acc[rt], 0, 0, 0);
            acc[rt] = __builtin_amdgcn_mfma_f32_16x16x32_f16(ah[rt], blo, acc[rt], 0, 0, 0);
        }
    }

    // ---- epilogue: wave w owns cols [w*16, w*16+16) ----
    float bv = bias[w * 16 + l15];

    if (doNormRelu) {
#pragma unroll
        for (int rt = 0; rt < 4; ++rt)
#pragma unroll
            for (int rr = 0; rr < 4; ++rr) {
                float vx = acc[rt][rr] + bv;
                float s = vx * vx;
                s += __shfl_xor(s, 1);
                s += __shfl_xor(s, 2);
                s += __shfl_xor(s, 4);
                s += __shfl_xor(s, 8);
                if (l15 == 0) rs[rt * 16 + quad * 4 + rr][w] = s;
            }
        __syncthreads();
#pragma unroll
        for (int rt = 0; rt < 4; ++rt)
#pragma unroll
            for (int rr = 0; rr < 4; ++rr) {
                int row = rt * 16 + quad * 4 + rr;
                int nn = nodeBase + row;
                if (nn < N_NODES) {
                    float tot = rs[row][0] + rs[row][1] + rs[row][2] + rs[row][3]
                              + rs[row][4] + rs[row][5] + rs[row][6] + rs[row][7];
                    float sc = 1.0f / fmaxf(sqrtf(tot), 1e-12f);
                    float vx = fmaxf((acc[rt][rr] + bv) * sc, 0.f);
                    outH[(size_t)nn * F + w * 16 + l15] = f2h(vx);
                }
            }
    } else {
#pragma unroll
        for (int rt = 0; rt < 4; ++rt)
#pragma unroll
            for (int rr = 0; rr < 4; ++rr) {
                int nn = nodeBase + rt * 16 + quad * 4 + rr;
                if (nn < N_NODES)
                    outF[(size_t)nn * F + w * 16 + l15] = acc[rt][rr] + bv;
            }
    }
}

extern "C" void kernel_launch(void* const* d_in, const int* in_sizes, int n_in,
                              void* d_out, int out_size, void* d_ws, size_t ws_size,
                              hipStream_t stream)
{
    const float* x   = (const float*)d_in[0];
    const float* Ws1 = (const float*)d_in[1];
    const float* Wn1 = (const float*)d_in[2];
    const float* b1  = (const float*)d_in[3];
    const float* Ws2 = (const float*)d_in[4];
    const float* Wn2 = (const float*)d_in[5];
    const float* b2  = (const float*)d_in[6];
    const int* edge_index = (const int*)d_in[7];
    const int* edge_type  = (const int*)d_in[8];

    const int* srcA = edge_index;
    const int* dstA = edge_index + N_EDGES;

    // workspace layout (~30 MB; keep small — the harness poison fill scales with it)
    unsigned short* x16 = (unsigned short*)d_ws;             // N*128 u16 = 12.8 MB
    unsigned short* h1  = x16 + (size_t)N_NODES * F;         // N*128 u16
    unsigned short* Wh  = h1 + (size_t)N_NODES * F;          // 2*WELEM u16
    unsigned short* Wl  = Wh + (size_t)2 * WELEM;            // 2*WELEM u16
    float* bavg = (float*)(Wl + (size_t)2 * WELEM);          // 256 f32
    int* counts = (int*)(bavg + 2 * F);                      // N_SEG + 260 (off + pad)
    int* cursor = counts + (N_SEG + 260);                    // N_SEG
    int* bsum   = cursor + N_SEG;                            // 256
    unsigned* perm = (unsigned*)(bsum + 256);                // N_EDGES u32 = 2.4 MB
    int* off = counts;                                       // alias after scan3

    // prep: weights + bias + fp16 cast of x (single launch)
    hipLaunchKernelGGL(prep, dim3(BW_BLOCKS + CAST_BLOCKS), dim3(256), 0, stream,
                       x, Ws1, Wn1, b1, Ws2, Wn2, b2, x16, Wh, Wl, bavg);

    // CSR build (shared by both layers)
    hipMemsetAsync(counts, 0, (size_t)N_SEG * sizeof(int), stream);
    hipLaunchKernelGGL(hist_kernel, dim3((N_EDGES + 255) / 256), dim3(256), 0, stream,
                       dstA, edge_type, counts);
    hipLaunchKernelGGL(scan1, dim3(SCAN_BLK), dim3(256), 0, stream, counts, bsum);
    hipLaunchKernelGGL(scan2, dim3(1), dim3(256), 0, stream, bsum);
    hipLaunchKernelGGL(scan3, dim3((N_SEG + 257 + 255) / 256), dim3(256), 0, stream,
                       counts, bsum, cursor);
    hipLaunchKernelGGL(permute_kernel, dim3((N_EDGES + 255) / 256), dim3(256), 0, stream,
                       srcA, dstA, edge_type, cursor, perm);

    const int fusedGrid = (N_NODES + 63) / 64;    // 782

    // ---------- layer 1 ----------
    hipLaunchKernelGGL(fused_layer, dim3(fusedGrid), dim3(512), 0, stream,
                       x16, perm, off, Wh, Wl, bavg,
                       (float*)nullptr, h1, 1);

    // ---------- layer 2 ----------
    hipLaunchKernelGGL(fused_layer, dim3(fusedGrid), dim3(512), 0, stream,
                       h1, perm, off, Wh + WELEM, Wl + WELEM, bavg + F,
                       (float*)d_out, (unsigned short*)nullptr, 0);
}

// Round 7
// 277.750 us; speedup vs baseline: 1.2245x; 1.2245x over previous
//
#include <hip/hip_runtime.h>
#include <math.h>

#define N_NODES 50000
#define N_EDGES 600000
#define F 128
#define NT 4
#define NKTG 20                // K tiles of 32 (640 total K)
#define NCT 8                  // out-col tiles of 16 (128/16)
#define N_SEG (NT * N_NODES)   // 200000
#define SCAN_BLK 196           // ceil(N_SEG / 1024)
#define WELEM (NKTG * NCT * 64 * 8)  // 81920 fp16 elements per layer
#define PER_LAYER (NKTG * NCT * 64)  // 10240 weight fragments
#define BW_BLOCKS 81           // build_w portion of prep grid (81*256 = 20736)
#define CAST_BLOCKS 12500      // cast portion (3.2M u32 / 256)

typedef __attribute__((ext_vector_type(8))) _Float16 f16x8;
typedef __attribute__((ext_vector_type(4))) float f32x4;

__device__ __forceinline__ unsigned short f2h(float f) {
    _Float16 h = (_Float16)f;
    return __builtin_bit_cast(unsigned short, h);
}
__device__ __forceinline__ float h2f(unsigned short u) {
    return (float)__builtin_bit_cast(_Float16, u);
}
__device__ __forceinline__ unsigned pack2h(float a, float b) {
    return (unsigned)f2h(a) | ((unsigned)f2h(b) << 16);
}

// ---- prep: build combined weights (fp16 hi/lo, frag order) + bias + cast x ----
__global__ __launch_bounds__(256) void prep(
    const float* __restrict__ x,
    const float* __restrict__ Ws1, const float* __restrict__ Wn1, const float* __restrict__ b1,
    const float* __restrict__ Ws2, const float* __restrict__ Wn2, const float* __restrict__ b2,
    unsigned short* __restrict__ x16,
    unsigned short* __restrict__ Wh, unsigned short* __restrict__ Wl,
    float* __restrict__ bavg)
{
    if (blockIdx.x >= BW_BLOCKS) {
        int i = (blockIdx.x - BW_BLOCKS) * 256 + threadIdx.x;
        if (i < N_NODES * 64) {
            float2 v = ((const float2*)x)[i];
            ((unsigned*)x16)[i] = pack2h(v.x, v.y);
        }
        return;
    }
    int idx = blockIdx.x * 256 + threadIdx.x;
    if (idx < 2 * PER_LAYER) {
        int l = idx >= PER_LAYER;
        int rem = idx - l * PER_LAYER;
        int lane = rem & 63;
        int ct = (rem >> 6) & 7;
        int ktg = (rem >> 6) >> 3;
        const float* Wsl = l ? Ws2 : Ws1;
        const float* Wnl = l ? Wn2 : Wn1;
        unsigned short* oh = Wh + (size_t)l * WELEM + (size_t)rem * 8;
        unsigned short* ol = Wl + (size_t)l * WELEM + (size_t)rem * 8;
        int c = ct * 16 + (lane & 15);
        int kb = ktg * 32 + (lane >> 4) * 8;
#pragma unroll
        for (int j = 0; j < 8; ++j) {
            int k = kb + j;
            float v;
            if (k < F) {
                v = 0.25f * (Wsl[(0 * F + k) * F + c] + Wsl[(1 * F + k) * F + c] +
                             Wsl[(2 * F + k) * F + c] + Wsl[(3 * F + k) * F + c]);
            } else {
                int t = (k - F) >> 7;
                int kk = (k - F) & (F - 1);
                v = 0.25f * Wnl[((size_t)t * F + kk) * F + c];
            }
            _Float16 hh = (_Float16)v;
            oh[j] = __builtin_bit_cast(unsigned short, hh);
            ol[j] = f2h(v - (float)hh);
        }
    } else {
        int k = idx - 2 * PER_LAYER;
        if (k < 2 * F) {
            int l = k >> 7;
            int j = k & (F - 1);
            const float* bl = l ? b2 : b1;
            bavg[k] = 0.25f * (bl[j] + bl[F + j] + bl[2 * F + j] + bl[3 * F + j]);
        }
    }
}

// ---------------- CSR build: seg = dst*4 + t ----------------
__global__ __launch_bounds__(256) void hist_kernel(
    const int* __restrict__ dstA, const int* __restrict__ typA, int* __restrict__ counts)
{
    int e = blockIdx.x * 256 + threadIdx.x;
    if (e < N_EDGES) atomicAdd(&counts[dstA[e] * NT + typA[e]], 1);
}

__global__ __launch_bounds__(256) void scan1(int* __restrict__ counts, int* __restrict__ bsum)
{
    __shared__ int sh[256];
    int t = threadIdx.x;
    int base = blockIdx.x * 1024 + t * 4;
    int v[4];
    int tot = 0;
#pragma unroll
    for (int j = 0; j < 4; ++j) {
        int i = base + j;
        v[j] = (i < N_SEG) ? counts[i] : 0;
        tot += v[j];
    }
    sh[t] = tot;
    __syncthreads();
    for (int ofs = 1; ofs < 256; ofs <<= 1) {
        int add = (t >= ofs) ? sh[t - ofs] : 0;
        __syncthreads();
        sh[t] += add;
        __syncthreads();
    }
    int excl = (t > 0) ? sh[t - 1] : 0;
    if (t == 255) bsum[blockIdx.x] = sh[255];
#pragma unroll
    for (int j = 0; j < 4; ++j) {
        int i = base + j;
        if (i < N_SEG) counts[i] = excl;
        excl += v[j];
    }
}

__global__ __launch_bounds__(256) void scan2(int* __restrict__ bsum)
{
    __shared__ int sh[256];
    int t = threadIdx.x;
    sh[t] = (t < SCAN_BLK) ? bsum[t] : 0;
    __syncthreads();
    for (int ofs = 1; ofs < 256; ofs <<= 1) {
        int add = (t >= ofs) ? sh[t - ofs] : 0;
        __syncthreads();
        sh[t] += add;
        __syncthreads();
    }
    int excl = (t > 0) ? sh[t - 1] : 0;
    if (t < SCAN_BLK) bsum[t] = excl;
}

// finalize offsets in place; pad [N_SEG, N_SEG+256] with N_EDGES so the fused
// kernel's per-wave boundary loads past the last real node read empty segments
__global__ __launch_bounds__(256) void scan3(
    int* __restrict__ counts, const int* __restrict__ bsum, int* __restrict__ cursor)
{
    int i = blockIdx.x * 256 + threadIdx.x;
    if (i < N_SEG) {
        int v = counts[i] + bsum[i >> 10];
        counts[i] = v;
        cursor[i] = v;
    } else if (i <= N_SEG + 256) {
        counts[i] = N_EDGES;
    }
}

// permute: bucket-sorted edges; payload = H-row dword offset (src*64)
__global__ __launch_bounds__(256) void permute_kernel(
    const int* __restrict__ srcA, const int* __restrict__ dstA, const int* __restrict__ typA,
    int* __restrict__ cursor, unsigned* __restrict__ perm)
{
    int e = blockIdx.x * 256 + threadIdx.x;
    if (e < N_EDGES) {
        int t = typA[e];
        int seg = dstA[e] * NT + t;
        int pos = atomicAdd(&cursor[seg], 1);
        perm[pos] = (unsigned)(srcA[e] * 64);
    }
}

// ================== fused layer (32-node tiles, 4 waves, 4 blocks/CU) ==================
// out[N,128] = [H | mean_t(H[src])][N,640] @ B[640,128] + bias (+norm/relu)
// Phase 1: chain-free TRIPLE-buffered gather of per-(node,type) means into the
// LDS Agg tile (scale applied at flush). One barrier. Phase 2: 20-K-tile MFMA
// GEMM (self-H fragments read straight from global — L1-hot) + fused epilogue.

// flush current segment's mean into the LDS Agg tile
#define FLUSH_SEG() do {                                                      \
    float inv_ = 1.0f / fmaxf((float)(nextB - segStart), 1.0f);               \
    AGd[(w << 3) + (cur >> 2)][((cur & 3) << 6) + lane] =                     \
        pack2h(accx * inv_, accy * inv_);                                     \
    accx = 0.f; accy = 0.f;                                                   \
    segStart = nextB;                                                         \
    cur++;                                                                    \
    nextB = __builtin_amdgcn_readlane(vb, cur + 1 < 32 ? cur + 1 : 32);       \
} while (0)

// advance the 64-entry perm window so the batch starting at EN is fully inside
#define ADVW(EN) do {                                                         \
    if ((EN) - pbase >= 64) {                                                 \
        pbase += 64;                                                          \
        P0 = P1;                                                              \
        int i2_ = pbase + 64 + lane;                                          \
        i2_ = i2_ < N_EDGES - 1 ? i2_ : N_EDGES - 1;                          \
        P1 = P[i2_];                                                          \
    }                                                                         \
} while (0)

// issue 16-deep batch B_ into (UV, NB)
#define ISSUE(B_, UV, NB) do {                                                \
    int e_ = s0 + ((B_) << 4);                                                \
    int r_ = eend - e_;                                                       \
    NB = r_ > 16 ? 16 : (r_ > 0 ? r_ : 0);                                    \
    _Pragma("unroll")                                                         \
    for (int j_ = 0; j_ < 16; ++j_) {                                         \
        if (j_ < NB) {                                                        \
            int idx_ = e_ + j_ - pbase;                                       \
            unsigned ow_ = (unsigned)__builtin_amdgcn_readlane((int)P0, idx_); \
            UV[j_] = H32[(size_t)ow_ + lane];                                 \
        }                                                                     \
    }                                                                         \
} while (0)

// consume batch B_ (flush at segment boundaries)
#define CONSUME(B_, UV, NB) do {                                              \
    int e_ = s0 + ((B_) << 4);                                                \
    _Pragma("unroll")                                                         \
    for (int j_ = 0; j_ < 16; ++j_) {                                         \
        if (j_ < NB) {                                                        \
            int ge_ = e_ + j_;                                                \
            while (ge_ >= nextB) { FLUSH_SEG(); }                             \
            accx += h2f((unsigned short)(UV[j_] & 0xffffu));                  \
            accy += h2f((unsigned short)(UV[j_] >> 16));                      \
        }                                                                     \
    }                                                                         \
} while (0)

__global__ __launch_bounds__(256, 4) void fused_layer(
    const unsigned short* __restrict__ Hin,   // [N,128] fp16 (self + gather source)
    const unsigned* __restrict__ perm,        // bucketed H-row dword offsets
    const int* __restrict__ off,              // [N_SEG+257], tail = N_EDGES
    const unsigned short* __restrict__ Wh,    // frag-ordered fp16 hi (this layer)
    const unsigned short* __restrict__ Wl,    // frag-ordered fp16 lo
    const float* __restrict__ bias,           // 128 fp32
    float* __restrict__ outF,                 // fp32 output (layer 2)
    unsigned short* __restrict__ outH,        // fp16 output (layer 1: norm+relu)
    int doNormRelu)
{
    __shared__ unsigned AGd[32][261];         // Agg tile [32 nodes][512 halves], dword view
    __shared__ float rs[32][4];               // row sumsq partials (L1 epilogue)

    const int tid = threadIdx.x;
    const int lane = tid & 63;
    const int w = tid >> 6;                   // 0..3
    const int quad = lane >> 4;
    const int l15 = lane & 15;
    const int nodeBase = blockIdx.x * 32;

    // ---- gather phase: per-wave 8 nodes = 32 (node,type) segments ----
    const unsigned* H32 = (const unsigned*)Hin;
    const unsigned* P = perm;
    const int n0 = nodeBase + w * 8;

    int bl = lane < 32 ? lane : 32;
    int vb = off[n0 * 4 + bl];                // 33 segment boundaries

    int s0   = __builtin_amdgcn_readfirstlane(vb);
    int eend = __builtin_amdgcn_readlane(vb, 32);

    int pbase = s0;
    int i0 = pbase + lane;          i0 = i0 < N_EDGES - 1 ? i0 : N_EDGES - 1;
    int i1 = pbase + 64 + lane;     i1 = i1 < N_EDGES - 1 ? i1 : N_EDGES - 1;
    unsigned P0 = P[i0];
    unsigned P1 = P[i1];

    int cur = 0;
    int segStart = s0;
    int nextB = __builtin_amdgcn_readlane(vb, 1);
    float accx = 0.f, accy = 0.f;

    int nBatch = (eend - s0 + 15) >> 4;
    if (nBatch > 0) {
        unsigned uvA[16], uvB[16], uvC[16];
        int nbA = 0, nbB = 0, nbC = 0;

        ISSUE(0, uvA, nbA);
        if (nBatch > 1) { ADVW(s0 + 16); ISSUE(1, uvB, nbB); }

        int b = 0;
        while (true) {
            if (b + 2 < nBatch) { ADVW(s0 + ((b + 2) << 4)); ISSUE(b + 2, uvC, nbC); }
            else nbC = 0;
            CONSUME(b, uvA, nbA);
            if (++b >= nBatch) break;

            if (b + 2 < nBatch) { ADVW(s0 + ((b + 2) << 4)); ISSUE(b + 2, uvA, nbA); }
            else nbA = 0;
            CONSUME(b, uvB, nbB);
            if (++b >= nBatch) break;

            if (b + 2 < nBatch) { ADVW(s0 + ((b + 2) << 4)); ISSUE(b + 2, uvB, nbB); }
            else nbB = 0;
            CONSUME(b, uvC, nbC);
            if (++b >= nBatch) break;
        }
    }
    while (cur < 32) { FLUSH_SEG(); }         // flush trailing empty segments

    __syncthreads();                          // Agg staged

    // ---- GEMM phase: [32,640] @ [640,128]; A from global (self) + LDS (agg) ----
    f32x4 acc[2][2];
#pragma unroll
    for (int rt = 0; rt < 2; ++rt)
#pragma unroll
        for (int ci = 0; ci < 2; ++ci)
            acc[rt][ci] = (f32x4){0.f, 0.f, 0.f, 0.f};

    const f16x8* BH = (const f16x8*)Wh;
    const f16x8* BL = (const f16x8*)Wl;

    // clamped self rows for this thread's fragment lanes
    int selfRow[2];
#pragma unroll
    for (int rt = 0; rt < 2; ++rt) {
        int n = nodeBase + rt * 16 + l15;
        selfRow[rt] = n < N_NODES ? n : N_NODES - 1;
    }

#pragma unroll 4
    for (int ktg = 0; ktg < NKTG; ++ktg) {
        f16x8 bh[2], blo[2];
#pragma unroll
        for (int ci = 0; ci < 2; ++ci) {
            int fi = (ktg * NCT + (w * 2 + ci)) * 64 + lane;
            bh[ci]  = BH[fi];
            blo[ci] = BL[fi];
        }
        f16x8 ah[2];
        if (ktg < 4) {
#pragma unroll
            for (int rt = 0; rt < 2; ++rt)
                ah[rt] = *(const f16x8*)(Hin + (size_t)selfRow[rt] * F + ktg * 32 + quad * 8);
        } else {
#pragma unroll
            for (int rt = 0; rt < 2; ++rt) {
                int row = rt * 16 + l15;
                int cd = ((ktg - 4) << 4) + (quad << 2);
                uint4 t4;
                t4.x = AGd[row][cd];
                t4.y = AGd[row][cd + 1];
                t4.z = AGd[row][cd + 2];
                t4.w = AGd[row][cd + 3];
                ah[rt] = __builtin_bit_cast(f16x8, t4);
            }
        }
#pragma unroll
        for (int rt = 0; rt < 2; ++rt)
#pragma unroll
            for (int ci = 0; ci < 2; ++ci) {
                acc[rt][ci] = __builtin_amdgcn_mfma_f32_16x16x32_f16(ah[rt], bh[ci],  acc[rt][ci], 0, 0, 0);
                acc[rt][ci] = __builtin_amdgcn_mfma_f32_16x16x32_f16(ah[rt], blo[ci], acc[rt][ci], 0, 0, 0);
            }
    }

    // ---- epilogue: wave w owns cols [w*32, w*32+32) ----
    float bv0 = bias[w * 32 + l15];
    float bv1 = bias[w * 32 + 16 + l15];

    if (doNormRelu) {
#pragma unroll
        for (int rt = 0; rt < 2; ++rt)
#pragma unroll
            for (int rr = 0; rr < 4; ++rr) {
                float vx = acc[rt][0][rr] + bv0;
                float vy = acc[rt][1][rr] + bv1;
                float s = vx * vx + vy * vy;
                s += __shfl_xor(s, 1);
                s += __shfl_xor(s, 2);
                s += __shfl_xor(s, 4);
                s += __shfl_xor(s, 8);
                if (l15 == 0) rs[rt * 16 + quad * 4 + rr][w] = s;
            }
        __syncthreads();
#pragma unroll
        for (int rt = 0; rt < 2; ++rt)
#pragma unroll
            for (int rr = 0; rr < 4; ++rr) {
                int row = rt * 16 + quad * 4 + rr;
                int nn = nodeBase + row;
                if (nn < N_NODES) {
                    float tot = rs[row][0] + rs[row][1] + rs[row][2] + rs[row][3];
                    float sc = 1.0f / fmaxf(sqrtf(tot), 1e-12f);
                    float vx = fmaxf((acc[rt][0][rr] + bv0) * sc, 0.f);
                    float vy = fmaxf((acc[rt][1][rr] + bv1) * sc, 0.f);
                    outH[(size_t)nn * F + w * 32 + l15]      = f2h(vx);
                    outH[(size_t)nn * F + w * 32 + 16 + l15] = f2h(vy);
                }
            }
    } else {
#pragma unroll
        for (int rt = 0; rt < 2; ++rt)
#pragma unroll
            for (int rr = 0; rr < 4; ++rr) {
                int nn = nodeBase + rt * 16 + quad * 4 + rr;
                if (nn < N_NODES) {
                    float* o = outF + (size_t)nn * F + w * 32 + l15;
                    o[0]  = acc[rt][0][rr] + bv0;
                    o[16] = acc[rt][1][rr] + bv1;
                }
            }
    }
}

extern "C" void kernel_launch(void* const* d_in, const int* in_sizes, int n_in,
                              void* d_out, int out_size, void* d_ws, size_t ws_size,
                              hipStream_t stream)
{
    const float* x   = (const float*)d_in[0];
    const float* Ws1 = (const float*)d_in[1];
    const float* Wn1 = (const float*)d_in[2];
    const float* b1  = (const float*)d_in[3];
    const float* Ws2 = (const float*)d_in[4];
    const float* Wn2 = (const float*)d_in[5];
    const float* b2  = (const float*)d_in[6];
    const int* edge_index = (const int*)d_in[7];
    const int* edge_type  = (const int*)d_in[8];

    const int* srcA = edge_index;
    const int* dstA = edge_index + N_EDGES;

    // workspace layout (~30 MB)
    unsigned short* x16 = (unsigned short*)d_ws;             // N*128 u16 = 12.8 MB
    unsigned short* h1  = x16 + (size_t)N_NODES * F;         // N*128 u16
    unsigned short* Wh  = h1 + (size_t)N_NODES * F;          // 2*WELEM u16
    unsigned short* Wl  = Wh + (size_t)2 * WELEM;            // 2*WELEM u16
    float* bavg = (float*)(Wl + (size_t)2 * WELEM);          // 256 f32
    int* counts = (int*)(bavg + 2 * F);                      // N_SEG + 260 (off + pad)
    int* cursor = counts + (N_SEG + 260);                    // N_SEG
    int* bsum   = cursor + N_SEG;                            // 256
    unsigned* perm = (unsigned*)(bsum + 256);                // N_EDGES u32 = 2.4 MB
    int* off = counts;                                       // alias after scan3

    // prep: weights + bias + fp16 cast of x (single launch)
    hipLaunchKernelGGL(prep, dim3(BW_BLOCKS + CAST_BLOCKS), dim3(256), 0, stream,
                       x, Ws1, Wn1, b1, Ws2, Wn2, b2, x16, Wh, Wl, bavg);

    // CSR build (shared by both layers)
    hipMemsetAsync(counts, 0, (size_t)N_SEG * sizeof(int), stream);
    hipLaunchKernelGGL(hist_kernel, dim3((N_EDGES + 255) / 256), dim3(256), 0, stream,
                       dstA, edge_type, counts);
    hipLaunchKernelGGL(scan1, dim3(SCAN_BLK), dim3(256), 0, stream, counts, bsum);
    hipLaunchKernelGGL(scan2, dim3(1), dim3(256), 0, stream, bsum);
    hipLaunchKernelGGL(scan3, dim3((N_SEG + 257 + 255) / 256), dim3(256), 0, stream,
                       counts, bsum, cursor);
    hipLaunchKernelGGL(permute_kernel, dim3((N_EDGES + 255) / 256), dim3(256), 0, stream,
                       srcA, dstA, edge_type, cursor, perm);

    const int fusedGrid = (N_NODES + 31) / 32;    // 1563

    // ---------- layer 1 ----------
    hipLaunchKernelGGL(fused_layer, dim3(fusedGrid), dim3(256), 0, stream,
                       x16, perm, off, Wh, Wl, bavg,
                       (float*)nullptr, h1, 1);

    // ---------- layer 2 ----------
    hipLaunchKernelGGL(fused_layer, dim3(fusedGrid), dim3(256), 0, stream,
                       h1, perm, off, Wh + WELEM, Wl + WELEM, bavg + F,
                       (float*)d_out, (unsigned short*)nullptr, 0);
}